// Round 8
// baseline (76634.229 us; speedup 1.0000x reference)
//
#include <hip/hip_runtime.h>
#include <hip/hip_bf16.h>

#define DEV __device__ __forceinline__

DEV float fast_rcp(float x) {
#if __has_builtin(__builtin_amdgcn_rcpf)
  return __builtin_amdgcn_rcpf(x);
#else
  return 1.0f / x;
#endif
}
DEV float sigm(float x) { return fast_rcp(1.0f + __expf(-x)); }
DEV float tanh_f(float x) {
  float e = __expf(-2.0f * fabsf(x));
  float t = 1.0f - 2.0f * e * fast_rcp(1.0f + e);
  return copysignf(t, x);
}
DEV float lrelu(float x) { return x > 0.0f ? x : 0.01f * x; }

DEV float wave_sum(float v) {
#pragma unroll
  for (int m = 32; m; m >>= 1) v += __shfl_xor(v, m);
  return v;
}
DEV float wave_max(float v) {
#pragma unroll
  for (int m = 32; m; m >>= 1) v = fmaxf(v, __shfl_xor(v, m));
  return v;
}
DEV float dot4(float4 w, float4 x, float acc) {
  acc = fmaf(w.x, x.x, acc);
  acc = fmaf(w.y, x.y, acc);
  acc = fmaf(w.z, x.z, acc);
  acc = fmaf(w.w, x.w, acc);
  return acc;
}

// ---------------------------------------------------------------------------
// Batched 2-layer GRU, lane = sequence, wave-uniform weights.
// R4-R6 lesson: row-per-lane (per-lane weights) -> spill storm. This layout:
// weights are WAVE-UNIFORM LDS broadcasts, state is per-lane 16B-consecutive
// b128, accumulators are statically-indexed scalars.
// R7 lesson (absmax 3.30e-3 vs 3.18e-3 threshold): accumulation ORDER
// matters. One 128-fma sequential chain per gate doubled rounding error vs
// the R4-R6 split form. Fix: each 64-dot uses 4 partial accumulators
// (16-fma chains) combined pairwise, and x-side/h-side kept separate until
// the gate nonlinearity (matches reference xw + gh structure).
// __launch_bounds__(512,2): 256-VGPR cap, demand ~110 -> no spill possible.
//
// Block = 512 thr = 8 waves; batch 64 seqs (lane). Wave w owns units
// [8w, 8w+8): rows {j, 64+j, 128+j}. Weights staged one gate (64 rows,
// 16 KB) at a time through Ws; both layers run sequentially per timestep.
// PyTorch GRU: r=sig(xr+hr) z=sig(xz+hz) n=tanh(xn + r*hn), h=(1-z)n+z*h.
// LDS: Ws 16K + H0 16K + H1 16K + biases 3K + Wx0s 4.5K = 55.5 KB < 64 KB.
// ---------------------------------------------------------------------------
DEV void dot_stage_h(const float (*Ws)[64], const float4 (*H)[64], int ju,
                     int lane, float (&acc)[8]) {
  float p[4][8];
#pragma unroll
  for (int q = 0; q < 4; ++q)
#pragma unroll
    for (int u = 0; u < 8; ++u) p[q][u] = 0.0f;
#pragma unroll
  for (int q = 0; q < 4; ++q) {
#pragma unroll
    for (int c = 0; c < 4; ++c) {
      const int ch = q * 4 + c;
      const float4 h4 = H[ch][lane];  // per-lane, 16B-consecutive
#pragma unroll
      for (int u = 0; u < 8; ++u) {
        const float4 w4 = *(const float4*)(&Ws[ju + u][ch * 4]);  // uniform
        p[q][u] = dot4(w4, h4, p[q][u]);
      }
    }
  }
#pragma unroll
  for (int u = 0; u < 8; ++u)
    acc[u] += (p[0][u] + p[1][u]) + (p[2][u] + p[3][u]);
}

DEV void dot_stage_x(const float (*Ws)[64], const float* xp, int ju,
                     float (&acc)[8]) {
  float p[4][8];
#pragma unroll
  for (int q = 0; q < 4; ++q)
#pragma unroll
    for (int u = 0; u < 8; ++u) p[q][u] = 0.0f;
#pragma unroll
  for (int q = 0; q < 4; ++q) {
#pragma unroll
    for (int c = 0; c < 4; ++c) {
      const int ch = q * 4 + c;
      const float4 x4 = *(const float4*)(xp + ch * 4);  // per-lane global
#pragma unroll
      for (int u = 0; u < 8; ++u) {
        const float4 w4 = *(const float4*)(&Ws[ju + u][ch * 4]);
        p[q][u] = dot4(w4, x4, p[q][u]);
      }
    }
  }
#pragma unroll
  for (int u = 0; u < 8; ++u)
    acc[u] += (p[0][u] + p[1][u]) + (p[2][u] + p[3][u]);
}

template <int I0, bool WRITE_FULL>
__global__ __launch_bounds__(512, 2)
void gru2_batched(const float* __restrict__ xin, int sstride, int tstride, int T,
                  const float* __restrict__ Wih0, const float* __restrict__ Whh0,
                  const float* __restrict__ bih0, const float* __restrict__ bhh0,
                  const float* __restrict__ Wih1, const float* __restrict__ Whh1,
                  const float* __restrict__ bih1, const float* __restrict__ bhh1,
                  float* __restrict__ out_last, float* __restrict__ out_full) {
  constexpr bool BIGX = (I0 > 8);
  const int tid = threadIdx.x;
  const int lane = tid & 63;
  const int wave = tid >> 6;  // 0..7
  const int ju = wave * 8;    // unit-tile base
  const int seq = blockIdx.x * 64 + lane;

  __shared__ __align__(16) float Ws[64][64];   // weight stage (one gate)
  __shared__ __align__(16) float4 H0[16][64];  // [k-chunk][lane]
  __shared__ __align__(16) float4 H1[16][64];
  __shared__ float bi0[192], bh0[192], bi1[192], bh1[192];
  __shared__ float Wx0s[192][6];  // small-x weights (encoder layer0)

  // one-time loads: biases, small-x weights, zero state
  for (int e = tid; e < 192; e += 512) {
    bi0[e] = bih0[e]; bh0[e] = bhh0[e];
    bi1[e] = bih1[e]; bh1[e] = bhh1[e];
  }
  if constexpr (!BIGX) {
    for (int e = tid; e < 192 * I0; e += 512)
      Wx0s[e / I0][e % I0] = Wih0[e];
  }
  for (int e = tid; e < 16 * 64; e += 512) {
    ((float4*)H0)[e] = float4{0.f, 0.f, 0.f, 0.f};
    ((float4*)H1)[e] = float4{0.f, 0.f, 0.f, 0.f};
  }

  // separate x-side / h-side accumulators (reference: xw[t] + gh)
  float axr[8], axz[8], axn[8], ahr[8], ahz[8], ahn[8];

  for (int t = 0; t < T; ++t) {
    // ---- layer 0 ----
    float xr[BIGX ? 1 : I0];
    if constexpr (!BIGX) {
      const float* xp = xin + (size_t)seq * sstride + (size_t)t * tstride;
#pragma unroll
      for (int i = 0; i < I0; ++i) xr[i] = xp[i];
    }
#pragma unroll
    for (int u = 0; u < 8; ++u) {
      const int r0 = ju + u;
      ahr[u] = bh0[r0];
      ahz[u] = bh0[64 + r0];
      ahn[u] = bh0[128 + r0];
      axr[u] = bi0[r0];
      axz[u] = bi0[64 + r0];
      axn[u] = bi0[128 + r0];
    }
    for (int g = 0; g < 3; ++g) {
      __syncthreads();  // prior consumers of Ws done
#pragma unroll
      for (int q = 0; q < 2; ++q)
        ((float4*)Ws)[tid + q * 512] =
            ((const float4*)(Whh0 + g * 4096))[tid + q * 512];
      __syncthreads();  // Ws ready
      dot_stage_h(Ws, H0, ju, lane, g == 0 ? ahr : (g == 1 ? ahz : ahn));
    }
    if constexpr (BIGX) {
      const float* xp = xin + (size_t)seq * sstride + (size_t)t * tstride;
      for (int g = 0; g < 3; ++g) {
        __syncthreads();
#pragma unroll
        for (int q = 0; q < 2; ++q)
          ((float4*)Ws)[tid + q * 512] =
              ((const float4*)(Wih0 + g * 4096))[tid + q * 512];
        __syncthreads();
        dot_stage_x(Ws, xp, ju, g == 0 ? axr : (g == 1 ? axz : axn));
      }
    } else {
#pragma unroll
      for (int u = 0; u < 8; ++u) {
        const int r0 = ju + u;
#pragma unroll
        for (int i = 0; i < I0; ++i) {
          axr[u] = fmaf(Wx0s[r0][i], xr[i], axr[u]);
          axz[u] = fmaf(Wx0s[64 + r0][i], xr[i], axz[u]);
          axn[u] = fmaf(Wx0s[128 + r0][i], xr[i], axn[u]);
        }
      }
    }
    __syncthreads();  // all H0 reads done before update writes
#pragma unroll
    for (int u = 0; u < 8; ++u) {
      const float r = sigm(axr[u] + ahr[u]);
      const float z = sigm(axz[u] + ahz[u]);
      const float n = tanh_f(axn[u] + r * ahn[u]);
      const int j = ju + u;
      float* hp = (float*)&H0[j >> 2][lane] + (j & 3);
      *hp = (1.0f - z) * n + z * *hp;
    }

    // ---- layer 1 (x input = just-updated H0) ----
#pragma unroll
    for (int u = 0; u < 8; ++u) {
      const int r0 = ju + u;
      ahr[u] = bh1[r0];
      ahz[u] = bh1[64 + r0];
      ahn[u] = bh1[128 + r0];
      axr[u] = bi1[r0];
      axz[u] = bi1[64 + r0];
      axn[u] = bi1[128 + r0];
    }
    for (int g = 0; g < 3; ++g) {
      __syncthreads();
#pragma unroll
      for (int q = 0; q < 2; ++q)
        ((float4*)Ws)[tid + q * 512] =
            ((const float4*)(Whh1 + g * 4096))[tid + q * 512];
      __syncthreads();
      dot_stage_h(Ws, H1, ju, lane, g == 0 ? ahr : (g == 1 ? ahz : ahn));
    }
    for (int g = 0; g < 3; ++g) {
      __syncthreads();
#pragma unroll
      for (int q = 0; q < 2; ++q)
        ((float4*)Ws)[tid + q * 512] =
            ((const float4*)(Wih1 + g * 4096))[tid + q * 512];
      __syncthreads();
      dot_stage_h(Ws, H0, ju, lane, g == 0 ? axr : (g == 1 ? axz : axn));
    }
    __syncthreads();  // all H1/H0 reads done before update writes
#pragma unroll
    for (int u = 0; u < 8; ++u) {
      const float r = sigm(axr[u] + ahr[u]);
      const float z = sigm(axz[u] + ahz[u]);
      const float n = tanh_f(axn[u] + r * ahn[u]);
      const int j = ju + u;
      float* hp = (float*)&H1[j >> 2][lane] + (j & 3);
      const float hn = (1.0f - z) * n + z * *hp;
      *hp = hn;
      if constexpr (WRITE_FULL) {
        out_full[((size_t)seq * T + t) * 64 + j] = hn;
      } else {
        if (t == T - 1) out_last[(size_t)seq * 64 + j] = hn;
      }
    }
  }
}

// ---------------------------------------------------------------------------
// GAT algebraic prep: v_dst[d] = sum_e trans_W[e][d]*a[e], v_src with a[64+e];
// c_dst/c_src from trans_b.  vbuf = [v_dst(64) | v_src(64) | c_dst | c_src]
// ---------------------------------------------------------------------------
__global__ void gat_prep(const float* __restrict__ tW, const float* __restrict__ tb,
                         const float* __restrict__ a, float* __restrict__ vbuf) {
  const int d = threadIdx.x;  // 64 threads
  float vd = 0.0f, vs = 0.0f;
  for (int e = 0; e < 64; ++e) {
    float w = tW[e * 64 + d];
    vd = fmaf(w, a[e], vd);
    vs = fmaf(w, a[64 + e], vs);
  }
  vbuf[d] = vd;
  vbuf[64 + d] = vs;
  if (d == 0) {
    float cd = 0.0f, cs = 0.0f;
    for (int e = 0; e < 64; ++e) {
      cd = fmaf(tb[e], a[e], cd);
      cs = fmaf(tb[e], a[64 + e], cs);
    }
    vbuf[128] = cd;
    vbuf[129] = cs;
  }
}

// s_src[n], s_dst[n] per encoder row (one wave per row)
__global__ void gat_svals(const float* __restrict__ h_enc, const float* __restrict__ vbuf,
                          float* __restrict__ s_src, float* __restrict__ s_dst) {
  const int wave = (blockIdx.x * blockDim.x + threadIdx.x) >> 6;
  const int lane = threadIdx.x & 63;
  float h = h_enc[(size_t)wave * 64 + lane];
  float pd = h * vbuf[lane];
  float ps = h * vbuf[64 + lane];
  pd = wave_sum(pd);
  ps = wave_sum(ps);
  if (lane == 0) {
    s_dst[wave] = pd + vbuf[128];
    s_src[wave] = ps + vbuf[129];
  }
}

// ---------------------------------------------------------------------------
// Dense all-pairs attention per group k (m=512): softmax_j leaky(s_i+s_j),
// weighted sum of h[k,j,:], + residual. One wave per row i; p-buffer in LDS
// (wave-private, no block barriers in the row loop); h streamed from L2.
// grid = 20 groups * 128 tiles, block = 256 (4 rows).
// ---------------------------------------------------------------------------
__launch_bounds__(256)
__global__ void gat_attn(const float* __restrict__ h_enc,
                         const float* __restrict__ s_src,
                         const float* __restrict__ s_dst,
                         float* __restrict__ hout) {
  const int k = blockIdx.x >> 7;
  const int tile = blockIdx.x & 127;
  const int wv = threadIdx.x >> 6;
  const int lane = threadIdx.x & 63;
  const int i = tile * 4 + wv;
  __shared__ float sdbuf[512];
  __shared__ __align__(16) float pbuf[4][512];

  for (int u = threadIdx.x; u < 512; u += 256) sdbuf[u] = s_dst[k * 512 + u];
  __syncthreads();

  const float si = s_src[k * 512 + i];
  float ev[8];
  float mx = -1e30f;
#pragma unroll
  for (int u = 0; u < 8; ++u) {
    ev[u] = lrelu(si + sdbuf[lane + u * 64]);
    mx = fmaxf(mx, ev[u]);
  }
  mx = wave_max(mx);
  float lsum = 0.0f;
#pragma unroll
  for (int u = 0; u < 8; ++u) {
    float p = __expf(ev[u] - mx);
    pbuf[wv][lane + u * 64] = p;
    lsum += p;
  }
  lsum = wave_sum(lsum);
  const float inv = fast_rcp(lsum);

  const float* hk = h_enc + (size_t)k * 512 * 64;
  const float4* pv = (const float4*)pbuf[wv];
  float acc0 = 0.0f, acc1 = 0.0f;
#pragma unroll 2
  for (int jj = 0; jj < 128; ++jj) {
    float4 p = pv[jj];
    const float* hp = hk + (size_t)(jj * 4) * 64 + lane;
    acc0 = fmaf(p.x, hp[0], acc0);
    acc1 = fmaf(p.y, hp[64], acc1);
    acc0 = fmaf(p.z, hp[128], acc0);
    acc1 = fmaf(p.w, hp[192], acc1);
  }
  hout[((size_t)k * 512 + i) * 64 + lane] =
      (acc0 + acc1) * inv + hk[(size_t)i * 64 + lane];
}

// ---------------------------------------------------------------------------
// Post-GAT transform: h2 = fc(hout); pred head (k==19); z = tanh(al_in(h2))
// written in [i][k][64] layout for the ALSTM scan. One wave per row.
// fw used & dead BEFORE aw is loaded -> allocator reuses the same regs.
// ---------------------------------------------------------------------------
__launch_bounds__(256)
__global__ void gat_out(const float* __restrict__ hin,
                        const float* __restrict__ fcW, const float* __restrict__ fcb,
                        const float* __restrict__ fcoW, const float* __restrict__ fcob,
                        const float* __restrict__ alinW, const float* __restrict__ alinb,
                        float* __restrict__ zout, float* __restrict__ pred) {
  const int wv = threadIdx.x >> 6;
  const int lane = threadIdx.x & 63;
  const int n = blockIdx.x * 4 + wv;  // [0,10240)
  const int k = n >> 9;
  const int i = n & 511;
  __shared__ __align__(16) float rbuf[4][64];
  __shared__ __align__(16) float rbuf2[4][64];

  rbuf[wv][lane] = hin[(size_t)n * 64 + lane];
  float h2 = fcb[lane];
  {
    float4 fw[16];
    const float4* p1 = (const float4*)(fcW + lane * 64);
#pragma unroll
    for (int kk = 0; kk < 16; ++kk) fw[kk] = p1[kk];
    const float4* rv = (const float4*)rbuf[wv];
#pragma unroll
    for (int kk = 0; kk < 16; ++kk) h2 = dot4(fw[kk], rv[kk], h2);
  }

  if (k == 19) {  // pred head on last group
    float pv = lrelu(h2) * fcoW[lane];
    pv = wave_sum(pv);
    if (lane == 0) pred[i] = pv + fcob[0];
  }

  rbuf2[wv][lane] = h2;
  float zz = alinb[lane];
  {
    float4 aw[16];
    const float4* p2 = (const float4*)(alinW + lane * 64);
#pragma unroll
    for (int kk = 0; kk < 16; ++kk) aw[kk] = p2[kk];
    const float4* rv2 = (const float4*)rbuf2[wv];
#pragma unroll
    for (int kk = 0; kk < 16; ++kk) zz = dot4(aw[kk], rv2[kk], zz);
  }
  zout[((size_t)i * 20 + k) * 64 + lane] = tanh_f(zz);
}

// ---------------------------------------------------------------------------
// ALSTM head: scores = tanh(r @ att1.T + b1) @ att2.T, softmax over k (20),
// out_att = sum_k p_k r[:,k,:], alstm_out = [r_last ; out_att] @ al_out.T + b.
// One wave per sequence i. Split-K halves via shfl_xor(32).
// ---------------------------------------------------------------------------
__launch_bounds__(256)
__global__ void alstm_head(const float* __restrict__ r1,  // [512][20][64]
                           const float* __restrict__ W1,  // [32][64]
                           const float* __restrict__ b1,  // [32]
                           const float* __restrict__ W2,  // [32]
                           const float* __restrict__ Wo,  // [128]
                           const float* __restrict__ bo,  // [1]
                           float* __restrict__ alstm_out) {
  const int wv = threadIdx.x >> 6;
  const int lane = threadIdx.x & 63;
  const int i = blockIdx.x * 4 + wv;  // [0,512)
  const int e = lane & 31;   // att1 row
  const int kh = lane >> 5;  // K-half
  __shared__ __align__(16) float rbuf[4][64];
  __shared__ float scb[4][20];

  float4 w1r[8];
  {
    const float4* p = (const float4*)(W1 + e * 64 + kh * 32);
#pragma unroll
    for (int kk = 0; kk < 8; ++kk) w1r[kk] = p[kk];
  }
  const float b1e = kh ? 0.0f : b1[e];
  const float w2e = W2[e];

  for (int k = 0; k < 20; ++k) {
    rbuf[wv][lane] = r1[((size_t)i * 20 + k) * 64 + lane];
    float u = b1e;
    const float4* rp = (const float4*)(&rbuf[wv][kh * 32]);
#pragma unroll
    for (int kk = 0; kk < 8; ++kk) u = dot4(w1r[kk], rp[kk], u);
    u += __shfl_xor(u, 32);  // combine K-halves
    u = tanh_f(u) * w2e;
#pragma unroll
    for (int m = 16; m; m >>= 1) u += __shfl_xor(u, m);  // reduce rows e
    if (lane == 0) scb[wv][k] = u;
  }

  float mx = -1e30f;
#pragma unroll
  for (int k = 0; k < 20; ++k) mx = fmaxf(mx, scb[wv][k]);
  float p[20];
  float l = 0.0f;
#pragma unroll
  for (int k = 0; k < 20; ++k) {
    p[k] = __expf(scb[wv][k] - mx);
    l += p[k];
  }
  const float inv = fast_rcp(l);

  float oa = 0.0f, rlast = 0.0f;
#pragma unroll
  for (int k = 0; k < 20; ++k) {
    float rv = r1[((size_t)i * 20 + k) * 64 + lane];
    oa = fmaf(p[k], rv, oa);
    if (k == 19) rlast = rv;
  }
  oa *= inv;
  float v = fmaf(Wo[lane], rlast, Wo[64 + lane] * oa);
  v = wave_sum(v);
  if (lane == 0) alstm_out[i] = v + bo[0];
}

// ---------------------------------------------------------------------------
extern "C" void kernel_launch(void* const* d_in, const int* in_sizes, int n_in,
                              void* d_out, int out_size, void* d_ws, size_t ws_size,
                              hipStream_t stream) {
  const float* x      = (const float*)d_in[0];
  const float* Wih0   = (const float*)d_in[1];
  const float* Whh0   = (const float*)d_in[2];
  const float* bih0   = (const float*)d_in[3];
  const float* bhh0   = (const float*)d_in[4];
  const float* Wih1   = (const float*)d_in[5];
  const float* Whh1   = (const float*)d_in[6];
  const float* bih1   = (const float*)d_in[7];
  const float* bhh1   = (const float*)d_in[8];
  const float* transW = (const float*)d_in[9];
  const float* transb = (const float*)d_in[10];
  const float* a_vec  = (const float*)d_in[11];
  const float* fcW    = (const float*)d_in[12];
  const float* fcb    = (const float*)d_in[13];
  const float* fcoW   = (const float*)d_in[14];
  const float* fcob   = (const float*)d_in[15];
  const float* alinW  = (const float*)d_in[16];
  const float* alinb  = (const float*)d_in[17];
  const float* aWih0  = (const float*)d_in[18];
  const float* aWhh0  = (const float*)d_in[19];
  const float* abih0  = (const float*)d_in[20];
  const float* abhh0  = (const float*)d_in[21];
  const float* aWih1  = (const float*)d_in[22];
  const float* aWhh1  = (const float*)d_in[23];
  const float* abih1  = (const float*)d_in[24];
  const float* abhh1  = (const float*)d_in[25];
  const float* att1W  = (const float*)d_in[26];
  const float* att1b  = (const float*)d_in[27];
  const float* att2W  = (const float*)d_in[28];
  const float* aloutW = (const float*)d_in[29];
  const float* aloutb = (const float*)d_in[30];

  float* out = (float*)d_out;  // [0:512) alstm_out, [512:1024) pred

  float* W = (float*)d_ws;     // ~10.6 MB total
  float* h_enc = W; W += 10240 * 64;
  float* vbuf  = W; W += 256;
  float* s_src = W; W += 10240;
  float* s_dst = W; W += 10240;
  float* hout  = W; W += 10240 * 64;
  float* zbuf  = W; W += 512 * 20 * 64;
  float* r1    = W; W += 512 * 20 * 64;

  // 1) fused 2-layer GRU encoder over T=60, batch-64 blocks, last hidden only
  gru2_batched<6, false><<<160, 512, 0, stream>>>(
      x, 60 * 6, 6, 60, Wih0, Whh0, bih0, bhh0, Wih1, Whh1, bih1, bhh1,
      h_enc, nullptr);
  // 2) GAT score-vector prep
  gat_prep<<<1, 64, 0, stream>>>(transW, transb, a_vec, vbuf);
  // 3) per-row s_src/s_dst
  gat_svals<<<2560, 256, 0, stream>>>(h_enc, vbuf, s_src, s_dst);
  // 4) dense attention + residual
  gat_attn<<<2560, 256, 0, stream>>>(h_enc, s_src, s_dst, hout);
  // 5) fc + pred head + ALSTM input transform (z in [i][k][64])
  gat_out<<<2560, 256, 0, stream>>>(hout, fcW, fcb, fcoW, fcob, alinW, alinb,
                                    zbuf, out + 512);
  // 6) fused 2-layer ALSTM GRU over K=20, full sequence out
  gru2_batched<64, true><<<8, 512, 0, stream>>>(
      zbuf, 20 * 64, 64, 20, aWih0, aWhh0, abih0, abhh0, aWih1, aWhh1, abih1,
      abhh1, nullptr, r1);
  // 7) ALSTM attention head -> alstm_out
  alstm_head<<<128, 256, 0, stream>>>(r1, att1W, att1b, att2W, aloutW, aloutb,
                                      out);
}

// Round 9
// 54257.013 us; speedup vs baseline: 1.4124x; 1.4124x over previous
//
#include <hip/hip_runtime.h>
#include <hip/hip_bf16.h>

#define DEV __device__ __forceinline__

DEV float fast_rcp(float x) {
#if __has_builtin(__builtin_amdgcn_rcpf)
  return __builtin_amdgcn_rcpf(x);
#else
  return 1.0f / x;
#endif
}
DEV float sigm(float x) { return fast_rcp(1.0f + __expf(-x)); }
DEV float tanh_f(float x) {
  float e = __expf(-2.0f * fabsf(x));
  float t = 1.0f - 2.0f * e * fast_rcp(1.0f + e);
  return copysignf(t, x);
}
DEV float lrelu(float x) { return x > 0.0f ? x : 0.01f * x; }

DEV float wave_sum(float v) {
#pragma unroll
  for (int m = 32; m; m >>= 1) v += __shfl_xor(v, m);
  return v;
}
DEV float wave_max(float v) {
#pragma unroll
  for (int m = 32; m; m >>= 1) v = fmaxf(v, __shfl_xor(v, m));
  return v;
}
DEV float dot4(float4 w, float4 x, float acc) {
  acc = fmaf(w.x, x.x, acc);
  acc = fmaf(w.y, x.y, acc);
  acc = fmaf(w.z, x.z, acc);
  acc = fmaf(w.w, x.w, acc);
  return acc;
}

// ---------------------------------------------------------------------------
// Batched 2-layer GRU, lane = sequence, wave-uniform weights.
// R8 LESSON (the 148 GB disaster): `g==0 ? ahr : (g==1 ? ahz : ahn)` selected
// a local-array pointer at RUNTIME -> all accumulator arrays demoted to
// scratch; every fma became a scratch RMW (30 KB/thread/step, VALUBusy 1.3%).
// This version has NO runtime-selected local arrays: each gate is an
// explicit stage+dot sequence, r/z finished into scalars early.
// Block = 1024 thr = 16 waves; wave owns 4 units -> per-thread arrays are
// [4]: persistent <=16 floats, transients p0..p3[4]=16 -> ~80 VGPR demand
// vs 128 cap (__launch_bounds__(1024,4)) -> no spill possible.
// Weights staged one gate (64 rows, 16 KB) at a time through Ws (each thread
// copies exactly one float4); dot reads are wave-uniform broadcasts.
// H state: [chunk][lane] float4 -> per-lane 16B-consecutive ds_read_b128.
// Numerics (validated in R8, absmax 0): each 64-dot = 4 partial 16-fma
// chains combined pairwise; x-side and h-side separate until the gate.
// PyTorch GRU: r=sig(xr+hr) z=sig(xz+hz) n=tanh(xn + r*hn), h=(1-z)n+z*h.
// LDS: Ws 16K + H0 16K + H1 16K + biases 3K + Wx0s 4.5K = 55.5 KB < 64 KB.
// ---------------------------------------------------------------------------
DEV void dot_h(const float (*Ws)[64], const float4 (*H)[64], int ju, int lane,
               float (&acc)[4]) {
  float p0[4] = {0.f, 0.f, 0.f, 0.f}, p1[4] = {0.f, 0.f, 0.f, 0.f};
  float p2[4] = {0.f, 0.f, 0.f, 0.f}, p3[4] = {0.f, 0.f, 0.f, 0.f};
#pragma unroll
  for (int c = 0; c < 4; ++c) {
    const float4 h4 = H[c][lane];
#pragma unroll
    for (int u = 0; u < 4; ++u)
      p0[u] = dot4(*(const float4*)(&Ws[ju + u][c * 4]), h4, p0[u]);
  }
#pragma unroll
  for (int c = 4; c < 8; ++c) {
    const float4 h4 = H[c][lane];
#pragma unroll
    for (int u = 0; u < 4; ++u)
      p1[u] = dot4(*(const float4*)(&Ws[ju + u][c * 4]), h4, p1[u]);
  }
#pragma unroll
  for (int c = 8; c < 12; ++c) {
    const float4 h4 = H[c][lane];
#pragma unroll
    for (int u = 0; u < 4; ++u)
      p2[u] = dot4(*(const float4*)(&Ws[ju + u][c * 4]), h4, p2[u]);
  }
#pragma unroll
  for (int c = 12; c < 16; ++c) {
    const float4 h4 = H[c][lane];
#pragma unroll
    for (int u = 0; u < 4; ++u)
      p3[u] = dot4(*(const float4*)(&Ws[ju + u][c * 4]), h4, p3[u]);
  }
#pragma unroll
  for (int u = 0; u < 4; ++u)
    acc[u] += (p0[u] + p1[u]) + (p2[u] + p3[u]);
}

DEV void dot_x(const float (*Ws)[64], const float* xp, int ju,
               float (&acc)[4]) {
  float p0[4] = {0.f, 0.f, 0.f, 0.f}, p1[4] = {0.f, 0.f, 0.f, 0.f};
  float p2[4] = {0.f, 0.f, 0.f, 0.f}, p3[4] = {0.f, 0.f, 0.f, 0.f};
#pragma unroll
  for (int c = 0; c < 4; ++c) {
    const float4 x4 = *(const float4*)(xp + c * 4);
#pragma unroll
    for (int u = 0; u < 4; ++u)
      p0[u] = dot4(*(const float4*)(&Ws[ju + u][c * 4]), x4, p0[u]);
  }
#pragma unroll
  for (int c = 4; c < 8; ++c) {
    const float4 x4 = *(const float4*)(xp + c * 4);
#pragma unroll
    for (int u = 0; u < 4; ++u)
      p1[u] = dot4(*(const float4*)(&Ws[ju + u][c * 4]), x4, p1[u]);
  }
#pragma unroll
  for (int c = 8; c < 12; ++c) {
    const float4 x4 = *(const float4*)(xp + c * 4);
#pragma unroll
    for (int u = 0; u < 4; ++u)
      p2[u] = dot4(*(const float4*)(&Ws[ju + u][c * 4]), x4, p2[u]);
  }
#pragma unroll
  for (int c = 12; c < 16; ++c) {
    const float4 x4 = *(const float4*)(xp + c * 4);
#pragma unroll
    for (int u = 0; u < 4; ++u)
      p3[u] = dot4(*(const float4*)(&Ws[ju + u][c * 4]), x4, p3[u]);
  }
#pragma unroll
  for (int u = 0; u < 4; ++u)
    acc[u] += (p0[u] + p1[u]) + (p2[u] + p3[u]);
}

template <int I0, bool WRITE_FULL>
__global__ __launch_bounds__(1024, 4)
void gru2_batched(const float* __restrict__ xin, int sstride, int tstride, int T,
                  const float* __restrict__ Wih0, const float* __restrict__ Whh0,
                  const float* __restrict__ bih0, const float* __restrict__ bhh0,
                  const float* __restrict__ Wih1, const float* __restrict__ Whh1,
                  const float* __restrict__ bih1, const float* __restrict__ bhh1,
                  float* __restrict__ out_last, float* __restrict__ out_full) {
  constexpr bool BIGX = (I0 > 8);
  const int tid = threadIdx.x;
  const int lane = tid & 63;
  const int wave = tid >> 6;  // 0..15
  const int ju = wave * 4;    // unit-tile base (4 units per wave)
  const int seq = blockIdx.x * 64 + lane;

  __shared__ __align__(16) float Ws[64][64];   // weight stage (one gate)
  __shared__ __align__(16) float4 H0[16][64];  // [k-chunk][lane]
  __shared__ __align__(16) float4 H1[16][64];
  __shared__ float bi0[192], bh0[192], bi1[192], bh1[192];
  __shared__ float Wx0s[192][6];  // small-x weights (encoder layer0)

  auto stage = [&](const float* src) {
    __syncthreads();  // prior consumers of Ws done
    ((float4*)Ws)[tid] = ((const float4*)src)[tid];
    __syncthreads();  // Ws ready
  };

  // one-time loads: biases, small-x weights, zero state
  for (int e = tid; e < 192; e += 1024) {
    bi0[e] = bih0[e]; bh0[e] = bhh0[e];
    bi1[e] = bih1[e]; bh1[e] = bhh1[e];
  }
  if constexpr (!BIGX) {
    for (int e = tid; e < 192 * I0; e += 1024)
      Wx0s[e / I0][e % I0] = Wih0[e];
  }
  {
    ((float4*)H0)[tid] = float4{0.f, 0.f, 0.f, 0.f};
    ((float4*)H1)[tid] = float4{0.f, 0.f, 0.f, 0.f};
  }

  for (int t = 0; t < T; ++t) {
    const float* xp = xin + (size_t)seq * sstride + (size_t)t * tstride;
    float r4[4], z4[4], axn[4], ahn[4];

    // ================= layer 0 =================
    float xr[BIGX ? 1 : I0];
    if constexpr (!BIGX) {
#pragma unroll
      for (int i = 0; i < I0; ++i) xr[i] = xp[i];
    }
    {  // r gate
      float ax[4], ah[4];
#pragma unroll
      for (int u = 0; u < 4; ++u) { ax[u] = bi0[ju + u]; ah[u] = bh0[ju + u]; }
      stage(Whh0);
      dot_h(Ws, H0, ju, lane, ah);
      if constexpr (BIGX) {
        stage(Wih0);
        dot_x(Ws, xp, ju, ax);
      } else {
#pragma unroll
        for (int u = 0; u < 4; ++u)
#pragma unroll
          for (int i = 0; i < I0; ++i) ax[u] = fmaf(Wx0s[ju + u][i], xr[i], ax[u]);
      }
#pragma unroll
      for (int u = 0; u < 4; ++u) r4[u] = sigm(ax[u] + ah[u]);
    }
    {  // z gate
      float ax[4], ah[4];
#pragma unroll
      for (int u = 0; u < 4; ++u) { ax[u] = bi0[64 + ju + u]; ah[u] = bh0[64 + ju + u]; }
      stage(Whh0 + 4096);
      dot_h(Ws, H0, ju, lane, ah);
      if constexpr (BIGX) {
        stage(Wih0 + 4096);
        dot_x(Ws, xp, ju, ax);
      } else {
#pragma unroll
        for (int u = 0; u < 4; ++u)
#pragma unroll
          for (int i = 0; i < I0; ++i)
            ax[u] = fmaf(Wx0s[64 + ju + u][i], xr[i], ax[u]);
      }
#pragma unroll
      for (int u = 0; u < 4; ++u) z4[u] = sigm(ax[u] + ah[u]);
    }
    {  // n gate (keep ax/ah separate until after r*hn)
#pragma unroll
      for (int u = 0; u < 4; ++u) { axn[u] = bi0[128 + ju + u]; ahn[u] = bh0[128 + ju + u]; }
      stage(Whh0 + 8192);
      dot_h(Ws, H0, ju, lane, ahn);
      if constexpr (BIGX) {
        stage(Wih0 + 8192);
        dot_x(Ws, xp, ju, axn);
      } else {
#pragma unroll
        for (int u = 0; u < 4; ++u)
#pragma unroll
          for (int i = 0; i < I0; ++i)
            axn[u] = fmaf(Wx0s[128 + ju + u][i], xr[i], axn[u]);
      }
    }
    __syncthreads();  // all waves' H0 reads done before update
#pragma unroll
    for (int u = 0; u < 4; ++u) {
      const float n = tanh_f(axn[u] + r4[u] * ahn[u]);
      const int j = ju + u;
      float* hp = (float*)&H0[j >> 2][lane] + (j & 3);
      *hp = (1.0f - z4[u]) * n + z4[u] * *hp;
    }

    // ================= layer 1 (x = just-updated H0) =================
    {  // r gate
      float ax[4], ah[4];
#pragma unroll
      for (int u = 0; u < 4; ++u) { ax[u] = bi1[ju + u]; ah[u] = bh1[ju + u]; }
      stage(Whh1);  // leading barrier also publishes the H0 update
      dot_h(Ws, H1, ju, lane, ah);
      stage(Wih1);
      dot_h(Ws, H0, ju, lane, ax);
#pragma unroll
      for (int u = 0; u < 4; ++u) r4[u] = sigm(ax[u] + ah[u]);
    }
    {  // z gate
      float ax[4], ah[4];
#pragma unroll
      for (int u = 0; u < 4; ++u) { ax[u] = bi1[64 + ju + u]; ah[u] = bh1[64 + ju + u]; }
      stage(Whh1 + 4096);
      dot_h(Ws, H1, ju, lane, ah);
      stage(Wih1 + 4096);
      dot_h(Ws, H0, ju, lane, ax);
#pragma unroll
      for (int u = 0; u < 4; ++u) z4[u] = sigm(ax[u] + ah[u]);
    }
    {  // n gate
#pragma unroll
      for (int u = 0; u < 4; ++u) { axn[u] = bi1[128 + ju + u]; ahn[u] = bh1[128 + ju + u]; }
      stage(Whh1 + 8192);
      dot_h(Ws, H1, ju, lane, ahn);
      stage(Wih1 + 8192);
      dot_h(Ws, H0, ju, lane, axn);
    }
    __syncthreads();  // all waves' H1/H0 reads done before update
#pragma unroll
    for (int u = 0; u < 4; ++u) {
      const float n = tanh_f(axn[u] + r4[u] * ahn[u]);
      const int j = ju + u;
      float* hp = (float*)&H1[j >> 2][lane] + (j & 3);
      const float hn = (1.0f - z4[u]) * n + z4[u] * *hp;
      *hp = hn;
      if constexpr (WRITE_FULL) {
        out_full[((size_t)seq * T + t) * 64 + j] = hn;
      } else {
        if (t == T - 1) out_last[(size_t)seq * 64 + j] = hn;
      }
    }
  }
}

// ---------------------------------------------------------------------------
// GAT algebraic prep: v_dst[d] = sum_e trans_W[e][d]*a[e], v_src with a[64+e];
// c_dst/c_src from trans_b.  vbuf = [v_dst(64) | v_src(64) | c_dst | c_src]
// ---------------------------------------------------------------------------
__global__ void gat_prep(const float* __restrict__ tW, const float* __restrict__ tb,
                         const float* __restrict__ a, float* __restrict__ vbuf) {
  const int d = threadIdx.x;  // 64 threads
  float vd = 0.0f, vs = 0.0f;
  for (int e = 0; e < 64; ++e) {
    float w = tW[e * 64 + d];
    vd = fmaf(w, a[e], vd);
    vs = fmaf(w, a[64 + e], vs);
  }
  vbuf[d] = vd;
  vbuf[64 + d] = vs;
  if (d == 0) {
    float cd = 0.0f, cs = 0.0f;
    for (int e = 0; e < 64; ++e) {
      cd = fmaf(tb[e], a[e], cd);
      cs = fmaf(tb[e], a[64 + e], cs);
    }
    vbuf[128] = cd;
    vbuf[129] = cs;
  }
}

// s_src[n], s_dst[n] per encoder row (one wave per row)
__global__ void gat_svals(const float* __restrict__ h_enc, const float* __restrict__ vbuf,
                          float* __restrict__ s_src, float* __restrict__ s_dst) {
  const int wave = (blockIdx.x * blockDim.x + threadIdx.x) >> 6;
  const int lane = threadIdx.x & 63;
  float h = h_enc[(size_t)wave * 64 + lane];
  float pd = h * vbuf[lane];
  float ps = h * vbuf[64 + lane];
  pd = wave_sum(pd);
  ps = wave_sum(ps);
  if (lane == 0) {
    s_dst[wave] = pd + vbuf[128];
    s_src[wave] = ps + vbuf[129];
  }
}

// ---------------------------------------------------------------------------
// Dense all-pairs attention per group k (m=512): softmax_j leaky(s_i+s_j),
// weighted sum of h[k,j,:], + residual. One wave per row i; p-buffer in LDS
// (wave-private, no block barriers in the row loop); h streamed from L2.
// grid = 20 groups * 128 tiles, block = 256 (4 rows).
// ---------------------------------------------------------------------------
__launch_bounds__(256)
__global__ void gat_attn(const float* __restrict__ h_enc,
                         const float* __restrict__ s_src,
                         const float* __restrict__ s_dst,
                         float* __restrict__ hout) {
  const int k = blockIdx.x >> 7;
  const int tile = blockIdx.x & 127;
  const int wv = threadIdx.x >> 6;
  const int lane = threadIdx.x & 63;
  const int i = tile * 4 + wv;
  __shared__ float sdbuf[512];
  __shared__ __align__(16) float pbuf[4][512];

  for (int u = threadIdx.x; u < 512; u += 256) sdbuf[u] = s_dst[k * 512 + u];
  __syncthreads();

  const float si = s_src[k * 512 + i];
  float ev[8];
  float mx = -1e30f;
#pragma unroll
  for (int u = 0; u < 8; ++u) {
    ev[u] = lrelu(si + sdbuf[lane + u * 64]);
    mx = fmaxf(mx, ev[u]);
  }
  mx = wave_max(mx);
  float lsum = 0.0f;
#pragma unroll
  for (int u = 0; u < 8; ++u) {
    float p = __expf(ev[u] - mx);
    pbuf[wv][lane + u * 64] = p;
    lsum += p;
  }
  lsum = wave_sum(lsum);
  const float inv = fast_rcp(lsum);

  const float* hk = h_enc + (size_t)k * 512 * 64;
  const float4* pv = (const float4*)pbuf[wv];
  float acc0 = 0.0f, acc1 = 0.0f;
#pragma unroll 2
  for (int jj = 0; jj < 128; ++jj) {
    float4 p = pv[jj];
    const float* hp = hk + (size_t)(jj * 4) * 64 + lane;
    acc0 = fmaf(p.x, hp[0], acc0);
    acc1 = fmaf(p.y, hp[64], acc1);
    acc0 = fmaf(p.z, hp[128], acc0);
    acc1 = fmaf(p.w, hp[192], acc1);
  }
  hout[((size_t)k * 512 + i) * 64 + lane] =
      (acc0 + acc1) * inv + hk[(size_t)i * 64 + lane];
}

// ---------------------------------------------------------------------------
// Post-GAT transform: h2 = fc(hout); pred head (k==19); z = tanh(al_in(h2))
// written in [i][k][64] layout for the ALSTM scan. One wave per row.
// fw used & dead BEFORE aw is loaded -> allocator reuses the same regs.
// ---------------------------------------------------------------------------
__launch_bounds__(256)
__global__ void gat_out(const float* __restrict__ hin,
                        const float* __restrict__ fcW, const float* __restrict__ fcb,
                        const float* __restrict__ fcoW, const float* __restrict__ fcob,
                        const float* __restrict__ alinW, const float* __restrict__ alinb,
                        float* __restrict__ zout, float* __restrict__ pred) {
  const int wv = threadIdx.x >> 6;
  const int lane = threadIdx.x & 63;
  const int n = blockIdx.x * 4 + wv;  // [0,10240)
  const int k = n >> 9;
  const int i = n & 511;
  __shared__ __align__(16) float rbuf[4][64];
  __shared__ __align__(16) float rbuf2[4][64];

  rbuf[wv][lane] = hin[(size_t)n * 64 + lane];
  float h2 = fcb[lane];
  {
    float4 fw[16];
    const float4* p1 = (const float4*)(fcW + lane * 64);
#pragma unroll
    for (int kk = 0; kk < 16; ++kk) fw[kk] = p1[kk];
    const float4* rv = (const float4*)rbuf[wv];
#pragma unroll
    for (int kk = 0; kk < 16; ++kk) h2 = dot4(fw[kk], rv[kk], h2);
  }

  if (k == 19) {  // pred head on last group
    float pv = lrelu(h2) * fcoW[lane];
    pv = wave_sum(pv);
    if (lane == 0) pred[i] = pv + fcob[0];
  }

  rbuf2[wv][lane] = h2;
  float zz = alinb[lane];
  {
    float4 aw[16];
    const float4* p2 = (const float4*)(alinW + lane * 64);
#pragma unroll
    for (int kk = 0; kk < 16; ++kk) aw[kk] = p2[kk];
    const float4* rv2 = (const float4*)rbuf2[wv];
#pragma unroll
    for (int kk = 0; kk < 16; ++kk) zz = dot4(aw[kk], rv2[kk], zz);
  }
  zout[((size_t)i * 20 + k) * 64 + lane] = tanh_f(zz);
}

// ---------------------------------------------------------------------------
// ALSTM head: scores = tanh(r @ att1.T + b1) @ att2.T, softmax over k (20),
// out_att = sum_k p_k r[:,k,:], alstm_out = [r_last ; out_att] @ al_out.T + b.
// One wave per sequence i. Split-K halves via shfl_xor(32).
// ---------------------------------------------------------------------------
__launch_bounds__(256)
__global__ void alstm_head(const float* __restrict__ r1,  // [512][20][64]
                           const float* __restrict__ W1,  // [32][64]
                           const float* __restrict__ b1,  // [32]
                           const float* __restrict__ W2,  // [32]
                           const float* __restrict__ Wo,  // [128]
                           const float* __restrict__ bo,  // [1]
                           float* __restrict__ alstm_out) {
  const int wv = threadIdx.x >> 6;
  const int lane = threadIdx.x & 63;
  const int i = blockIdx.x * 4 + wv;  // [0,512)
  const int e = lane & 31;   // att1 row
  const int kh = lane >> 5;  // K-half
  __shared__ __align__(16) float rbuf[4][64];
  __shared__ float scb[4][20];

  float4 w1r[8];
  {
    const float4* p = (const float4*)(W1 + e * 64 + kh * 32);
#pragma unroll
    for (int kk = 0; kk < 8; ++kk) w1r[kk] = p[kk];
  }
  const float b1e = kh ? 0.0f : b1[e];
  const float w2e = W2[e];

  for (int k = 0; k < 20; ++k) {
    rbuf[wv][lane] = r1[((size_t)i * 20 + k) * 64 + lane];
    float u = b1e;
    const float4* rp = (const float4*)(&rbuf[wv][kh * 32]);
#pragma unroll
    for (int kk = 0; kk < 8; ++kk) u = dot4(w1r[kk], rp[kk], u);
    u += __shfl_xor(u, 32);  // combine K-halves
    u = tanh_f(u) * w2e;
#pragma unroll
    for (int m = 16; m; m >>= 1) u += __shfl_xor(u, m);  // reduce rows e
    if (lane == 0) scb[wv][k] = u;
  }

  float mx = -1e30f;
#pragma unroll
  for (int k = 0; k < 20; ++k) mx = fmaxf(mx, scb[wv][k]);
  float p[20];
  float l = 0.0f;
#pragma unroll
  for (int k = 0; k < 20; ++k) {
    p[k] = __expf(scb[wv][k] - mx);
    l += p[k];
  }
  const float inv = fast_rcp(l);

  float oa = 0.0f, rlast = 0.0f;
#pragma unroll
  for (int k = 0; k < 20; ++k) {
    float rv = r1[((size_t)i * 20 + k) * 64 + lane];
    oa = fmaf(p[k], rv, oa);
    if (k == 19) rlast = rv;
  }
  oa *= inv;
  float v = fmaf(Wo[lane], rlast, Wo[64 + lane] * oa);
  v = wave_sum(v);
  if (lane == 0) alstm_out[i] = v + bo[0];
}

// ---------------------------------------------------------------------------
extern "C" void kernel_launch(void* const* d_in, const int* in_sizes, int n_in,
                              void* d_out, int out_size, void* d_ws, size_t ws_size,
                              hipStream_t stream) {
  const float* x      = (const float*)d_in[0];
  const float* Wih0   = (const float*)d_in[1];
  const float* Whh0   = (const float*)d_in[2];
  const float* bih0   = (const float*)d_in[3];
  const float* bhh0   = (const float*)d_in[4];
  const float* Wih1   = (const float*)d_in[5];
  const float* Whh1   = (const float*)d_in[6];
  const float* bih1   = (const float*)d_in[7];
  const float* bhh1   = (const float*)d_in[8];
  const float* transW = (const float*)d_in[9];
  const float* transb = (const float*)d_in[10];
  const float* a_vec  = (const float*)d_in[11];
  const float* fcW    = (const float*)d_in[12];
  const float* fcb    = (const float*)d_in[13];
  const float* fcoW   = (const float*)d_in[14];
  const float* fcob   = (const float*)d_in[15];
  const float* alinW  = (const float*)d_in[16];
  const float* alinb  = (const float*)d_in[17];
  const float* aWih0  = (const float*)d_in[18];
  const float* aWhh0  = (const float*)d_in[19];
  const float* abih0  = (const float*)d_in[20];
  const float* abhh0  = (const float*)d_in[21];
  const float* aWih1  = (const float*)d_in[22];
  const float* aWhh1  = (const float*)d_in[23];
  const float* abih1  = (const float*)d_in[24];
  const float* abhh1  = (const float*)d_in[25];
  const float* att1W  = (const float*)d_in[26];
  const float* att1b  = (const float*)d_in[27];
  const float* att2W  = (const float*)d_in[28];
  const float* aloutW = (const float*)d_in[29];
  const float* aloutb = (const float*)d_in[30];

  float* out = (float*)d_out;  // [0:512) alstm_out, [512:1024) pred

  float* W = (float*)d_ws;     // ~10.6 MB total
  float* h_enc = W; W += 10240 * 64;
  float* vbuf  = W; W += 256;
  float* s_src = W; W += 10240;
  float* s_dst = W; W += 10240;
  float* hout  = W; W += 10240 * 64;
  float* zbuf  = W; W += 512 * 20 * 64;
  float* r1    = W; W += 512 * 20 * 64;

  // 1) fused 2-layer GRU encoder over T=60, batch-64 blocks, last hidden only
  gru2_batched<6, false><<<160, 1024, 0, stream>>>(
      x, 60 * 6, 6, 60, Wih0, Whh0, bih0, bhh0, Wih1, Whh1, bih1, bhh1,
      h_enc, nullptr);
  // 2) GAT score-vector prep
  gat_prep<<<1, 64, 0, stream>>>(transW, transb, a_vec, vbuf);
  // 3) per-row s_src/s_dst
  gat_svals<<<2560, 256, 0, stream>>>(h_enc, vbuf, s_src, s_dst);
  // 4) dense attention + residual
  gat_attn<<<2560, 256, 0, stream>>>(h_enc, s_src, s_dst, hout);
  // 5) fc + pred head + ALSTM input transform (z in [i][k][64])
  gat_out<<<2560, 256, 0, stream>>>(hout, fcW, fcb, fcoW, fcob, alinW, alinb,
                                    zbuf, out + 512);
  // 6) fused 2-layer ALSTM GRU over K=20, full sequence out
  gru2_batched<64, true><<<8, 1024, 0, stream>>>(
      zbuf, 20 * 64, 64, 20, aWih0, aWhh0, abih0, abhh0, aWih1, aWhh1, abih1,
      abhh1, nullptr, r1);
  // 7) ALSTM attention head -> alstm_out
  alstm_head<<<128, 256, 0, stream>>>(r1, att1W, att1b, att2W, aloutW, aloutb,
                                      out);
}